// Round 11
// baseline (256.379 us; speedup 1.0000x reference)
//
#include <hip/hip_runtime.h>

#define EPS 1e-5f
#define NSLOT 64   // spread-slot copies of the stats accumulators (64 floats each)
#define FLT_BIG 3.402823466e+38f

__device__ __forceinline__ float waveReduceSum(float v) {
    #pragma unroll
    for (int off = 32; off > 0; off >>= 1)
        v += __shfl_down(v, off, 64);
    return v;
}

// Butterfly-compaction reduction: NV stats spread across lanes.
template <int NV>
__device__ __forceinline__ float statReduce(float (&v)[NV], int lane) {
    #pragma unroll
    for (int b = 0; (1 << b) < NV; ++b) {
        const int d = 1 << b;
        const bool hi = (lane >> b) & 1;
        #pragma unroll
        for (int i = 0; i < (NV >> (b + 1)); ++i) {
            float kept = hi ? v[2 * i + 1] : v[2 * i];
            float sent = hi ? v[2 * i] : v[2 * i + 1];
            float recv = __shfl_xor(sent, d, 64);
            v[i] = kept + recv;
        }
    }
    float r = v[0];
    #pragma unroll
    for (int d = NV; d < 64; d <<= 1)
        r += __shfl_xor(r, d, 64);
    return r;
}

// ---------------- K0: zero the slot accumulators (16 KB) ----------------
__global__ __launch_bounds__(256) void k_zero(float4* __restrict__ slots) {
    const float4 z4 = {0.f, 0.f, 0.f, 0.f};
    #pragma unroll
    for (int q = 0; q < 4; ++q)
        slots[q * 256 + threadIdx.x] = z4;
}

// ---------------- K1: conv1 over the <=4 children of each pool-1 site.
// pooled[c] = gamma1[c]>=0 ? max_k conv[c] : min_k conv[c]   (8 floats/site).
__global__ __launch_bounds__(256, 4) void k_conv1pool(
        const float* __restrict__ f0, const float* __restrict__ W1,
        const float* __restrict__ b1, const float* __restrict__ gamma1,
        const int* __restrict__ nbr0, const int* __restrict__ pmap1,
        float* __restrict__ pmm, float* __restrict__ slots, int n1) {
    __shared__ float sred[16];
    int t = threadIdx.x;
    int lane = t & 63;
    if (t < 16) sred[t] = 0.f;
    __syncthreads();

    int i = blockIdx.x * blockDim.x + t;
    bool valid = (i < n1);
    int icl = valid ? i : (n1 - 1);
    int4 pm = ((const int4*)pmap1)[icl];
    if (!valid) { pm.x = -1; pm.y = -1; pm.z = -1; pm.w = -1; }
    int ch[4] = {pm.x, pm.y, pm.z, pm.w};

    float maxv[8], minv[8], red[16];
    #pragma unroll
    for (int c = 0; c < 8; ++c) { maxv[c] = -FLT_BIG; minv[c] = FLT_BIG; }
    #pragma unroll
    for (int c = 0; c < 16; ++c) red[c] = 0.f;

    #pragma unroll
    for (int p = 0; p < 2; ++p) {
        int c0 = ch[2 * p], c1 = ch[2 * p + 1];
        int j0 = c0 >= 0 ? c0 : 0;
        int j1 = c1 >= 0 ? c1 : 0;
        int idx0[9], idx1[9];
        #pragma unroll
        for (int k = 0; k < 9; ++k) idx0[k] = nbr0[(size_t)j0 * 9 + k];
        #pragma unroll
        for (int k = 0; k < 9; ++k) idx1[k] = nbr0[(size_t)j1 * 9 + k];
        float v0[9], v1[9];
        #pragma unroll
        for (int k = 0; k < 9; ++k) {
            int e = idx0[k]; float f = f0[e >= 0 ? e : 0]; v0[k] = e >= 0 ? f : 0.f;
        }
        #pragma unroll
        for (int k = 0; k < 9; ++k) {
            int e = idx1[k]; float f = f0[e >= 0 ? e : 0]; v1[k] = e >= 0 ? f : 0.f;
        }
        float a0[8], a1[8];
        #pragma unroll
        for (int c = 0; c < 8; ++c) { a0[c] = b1[c]; a1[c] = b1[c]; }
        #pragma unroll
        for (int k = 0; k < 9; ++k) {
            #pragma unroll
            for (int c = 0; c < 8; ++c) {
                float w = W1[k * 8 + c];
                a0[c] = fmaf(v0[k], w, a0[c]);
                a1[c] = fmaf(v1[k], w, a1[c]);
            }
        }
        if (c0 >= 0) {
            #pragma unroll
            for (int c = 0; c < 8; ++c) {
                red[c] += a0[c]; red[8 + c] += a0[c] * a0[c];
                maxv[c] = fmaxf(maxv[c], a0[c]); minv[c] = fminf(minv[c], a0[c]);
            }
        }
        if (c1 >= 0) {
            #pragma unroll
            for (int c = 0; c < 8; ++c) {
                red[c] += a1[c]; red[8 + c] += a1[c] * a1[c];
                maxv[c] = fmaxf(maxv[c], a1[c]); minv[c] = fminf(minv[c], a1[c]);
            }
        }
    }

    if (valid) {
        float sel[8];
        #pragma unroll
        for (int c = 0; c < 8; ++c)
            sel[c] = (gamma1[c] >= 0.f) ? maxv[c] : minv[c];
        float4* dst = (float4*)(pmm + (size_t)i * 8);
        dst[0] = make_float4(sel[0], sel[1], sel[2], sel[3]);
        dst[1] = make_float4(sel[4], sel[5], sel[6], sel[7]);
    }

    float tot = statReduce<16>(red, lane);
    if (lane < 16) atomicAdd(&sred[lane], tot);
    __syncthreads();
    if (t < 16)
        atomicAdd(&slots[(size_t)(blockIdx.x & (NSLOT - 1)) * 64 + t], sred[t]);
}

// ---------------- K1b: 1-block finalize of BN1 -> folded constants.
// g = relu(pv*sc + b0), sc = rsqrt(var+eps)*gamma1, b0 = beta1 - sc*mu.
__global__ __launch_bounds__(64) void k_bn1stats(
        const float* __restrict__ slots, const float* __restrict__ gamma1,
        const float* __restrict__ beta1, float* __restrict__ stats, float invn0) {
    __shared__ float st[16];
    int t = threadIdx.x;
    if (t < 16) {
        float s = 0.f;
        #pragma unroll 8
        for (int k = 0; k < NSLOT; ++k) s += slots[(size_t)k * 64 + t];
        st[t] = s;
    }
    __syncthreads();
    if (t < 8) {
        float mu  = st[t] * invn0;
        float var = st[8 + t] * invn0 - mu * mu;
        float sc  = rsqrtf(var + EPS) * gamma1[t];
        stats[t]     = sc;
        stats[8 + t] = beta1[t] - sc * mu;
    }
}

// ---------------- K2: sparse conv2 (8 -> 16), 2 points/thread.
// BN1 consts come pre-folded from k_bn1stats via uniform scalar loads (SGPRs):
// no per-block slots reduce, no bm/sc/bb VGPR state. Two independent gather
// streams per lane double memory-level parallelism.
__global__ __launch_bounds__(256, 4) void k_conv2(
        const float* __restrict__ pmm, const float* __restrict__ W2,
        const float* __restrict__ b2, const int* __restrict__ nbr1,
        const float* __restrict__ stats, float* __restrict__ x2,
        float* __restrict__ slots, int n1) {
    __shared__ float sred[32];
    int t = threadIdx.x;
    int lane = t & 63;
    if (t < 32) sred[t] = 0.f;
    __syncthreads();

    int nA = blockIdx.x * 512 + t;
    int nB = nA + 256;
    bool vA = (nA < n1), vB = (nB < n1);
    int iA = vA ? nA : (n1 - 1);
    int iB = vB ? nB : (n1 - 1);

    int idxA[9], idxB[9];
    #pragma unroll
    for (int k = 0; k < 9; ++k) idxA[k] = nbr1[(size_t)iA * 9 + k];
    #pragma unroll
    for (int k = 0; k < 9; ++k) idxB[k] = nbr1[(size_t)iB * 9 + k];

    float accA[16], accB[16];
    #pragma unroll
    for (int c = 0; c < 16; ++c) { accA[c] = b2[c]; accB[c] = b2[c]; }

    #pragma unroll
    for (int k = 0; k < 9; ++k) {
        const float4* bA = (const float4*)(pmm + (size_t)(idxA[k] >= 0 ? idxA[k] : 0) * 8);
        const float4* bB = (const float4*)(pmm + (size_t)(idxB[k] >= 0 ? idxB[k] : 0) * 8);
        float4 A0 = bA[0], A1 = bA[1];
        float4 B0 = bB[0], B1 = bB[1];
        float pA[8] = {A0.x, A0.y, A0.z, A0.w, A1.x, A1.y, A1.z, A1.w};
        float pB[8] = {B0.x, B0.y, B0.z, B0.w, B1.x, B1.y, B1.z, B1.w};
        float gA[8], gB[8];
        #pragma unroll
        for (int c = 0; c < 8; ++c) {
            float scc = stats[c], b0c = stats[8 + c];
            float zA = fmaxf(fmaf(pA[c], scc, b0c), 0.f);
            float zB = fmaxf(fmaf(pB[c], scc, b0c), 0.f);
            gA[c] = (idxA[k] >= 0) ? zA : 0.f;
            gB[c] = (idxB[k] >= 0) ? zB : 0.f;
        }
        #pragma unroll
        for (int ci = 0; ci < 8; ++ci) {
            #pragma unroll
            for (int c = 0; c < 16; ++c) {
                float w = W2[(k * 8 + ci) * 16 + c];
                accA[c] = fmaf(gA[ci], w, accA[c]);
                accB[c] = fmaf(gB[ci], w, accB[c]);
            }
        }
    }

    if (vA) {
        float4* dst = (float4*)(x2 + (size_t)nA * 16);
        #pragma unroll
        for (int q4 = 0; q4 < 4; ++q4)
            dst[q4] = make_float4(accA[q4 * 4], accA[q4 * 4 + 1],
                                  accA[q4 * 4 + 2], accA[q4 * 4 + 3]);
    } else {
        #pragma unroll
        for (int c = 0; c < 16; ++c) accA[c] = 0.f;
    }
    if (vB) {
        float4* dst = (float4*)(x2 + (size_t)nB * 16);
        #pragma unroll
        for (int q4 = 0; q4 < 4; ++q4)
            dst[q4] = make_float4(accB[q4 * 4], accB[q4 * 4 + 1],
                                  accB[q4 * 4 + 2], accB[q4 * 4 + 3]);
    } else {
        #pragma unroll
        for (int c = 0; c < 16; ++c) accB[c] = 0.f;
    }

    float red[32];
    #pragma unroll
    for (int c = 0; c < 16; ++c) {
        red[c] = accA[c] + accB[c];
        red[16 + c] = accA[c] * accA[c] + accB[c] * accB[c];
    }
    float tot = statReduce<32>(red, lane);
    if (lane < 32) atomicAdd(&sred[lane], tot);
    __syncthreads();
    if (t < 32)
        atomicAdd(&slots[(size_t)(blockIdx.x & (NSLOT - 1)) * 64 + 16 + t], sred[t]);
}

// ---------------- K3: finalize BN2 stats + BN2+ReLU fused into pool + FC(16->2) ----------------
__global__ __launch_bounds__(256) void k_pool2_fc(
        const float* __restrict__ x2, const int* __restrict__ pmap2,
        const float* __restrict__ slots, const float* __restrict__ gamma2,
        const float* __restrict__ beta2, const float* __restrict__ Wfc,
        const float* __restrict__ bfc, float* __restrict__ out,
        int n2, float invn) {
    __shared__ float sstat[32];
    int t = threadIdx.x;
    if (t < 64) {
        const float4* s4 = (const float4*)(slots + (size_t)t * 64 + 16);
        float vals[32];
        #pragma unroll
        for (int q = 0; q < 8; ++q) {
            float4 a = s4[q];
            vals[q * 4 + 0] = a.x; vals[q * 4 + 1] = a.y;
            vals[q * 4 + 2] = a.z; vals[q * 4 + 3] = a.w;
        }
        #pragma unroll
        for (int c = 0; c < 32; ++c) {
            float s = waveReduceSum(vals[c]);
            if (t == 0) sstat[c] = s;
        }
    }
    __syncthreads();

    int i = blockIdx.x * blockDim.x + t;
    if (i >= n2) return;

    float m[16], sc[16], bb[16];
    #pragma unroll
    for (int c = 0; c < 16; ++c) {
        float mu  = sstat[c] * invn;
        float var = sstat[16 + c] * invn - mu * mu;
        m[c]  = mu;
        sc[c] = rsqrtf(var + EPS) * gamma2[c];
        bb[c] = beta2[c];
    }

    int4 pm = ((const int4*)pmap2)[i];
    int idx[4] = {pm.x, pm.y, pm.z, pm.w};
    float best[16];
    #pragma unroll
    for (int c = 0; c < 16; ++c) best[c] = 0.f;
    #pragma unroll
    for (int k = 0; k < 4; ++k) {
        int j = idx[k] >= 0 ? idx[k] : 0;
        const float4* src = (const float4*)(x2 + (size_t)j * 16);
        #pragma unroll
        for (int q4 = 0; q4 < 4; ++q4) {
            float4 v4 = src[q4];
            float v[4] = {v4.x, v4.y, v4.z, v4.w};
            #pragma unroll
            for (int c = 0; c < 4; ++c) {
                int cc = q4 * 4 + c;
                float z = fmaxf(fmaf(v[c] - m[cc], sc[cc], bb[cc]), 0.f);
                z = (idx[k] >= 0) ? z : 0.f;
                best[cc] = fmaxf(best[cc], z);
            }
        }
    }
    float o0 = bfc[0], o1 = bfc[1];
    #pragma unroll
    for (int c = 0; c < 16; ++c) {
        o0 = fmaf(best[c], Wfc[c * 2 + 0], o0);
        o1 = fmaf(best[c], Wfc[c * 2 + 1], o1);
    }
    out[(size_t)i * 2 + 0] = o0;
    out[(size_t)i * 2 + 1] = o1;
}

extern "C" void kernel_launch(void* const* d_in, const int* in_sizes, int n_in,
                              void* d_out, int out_size, void* d_ws, size_t ws_size,
                              hipStream_t stream) {
    const float* f0     = (const float*)d_in[0];
    const float* W1     = (const float*)d_in[1];
    const float* b1     = (const float*)d_in[2];
    const float* gamma1 = (const float*)d_in[3];
    const float* beta1  = (const float*)d_in[4];
    const float* W2     = (const float*)d_in[5];
    const float* b2     = (const float*)d_in[6];
    const float* gamma2 = (const float*)d_in[7];
    const float* beta2  = (const float*)d_in[8];
    const float* Wfc    = (const float*)d_in[9];
    const float* bfc    = (const float*)d_in[10];
    const int*   nbr0   = (const int*)d_in[11];
    const int*   pmap1  = (const int*)d_in[12];
    const int*   nbr1   = (const int*)d_in[13];
    const int*   pmap2  = (const int*)d_in[14];

    const int n0 = in_sizes[0];
    const int n1 = in_sizes[12] / 4;
    const int n2 = in_sizes[14] / 4;

    float* ws    = (float*)d_ws;
    float* slots = ws;                              // NSLOT * 64 floats
    float* stats = ws + (size_t)NSLOT * 64;         // 16 floats (sc1, b01)
    float* pmm   = stats + 16;                      // n1*8 (selected raw extremum)
    float* x2    = pmm + (size_t)n1 * 8;            // n1*16

    const int B = 256;
    k_zero<<<1, B, 0, stream>>>((float4*)slots);
    k_conv1pool<<<(n1 + B - 1) / B, B, 0, stream>>>(f0, W1, b1, gamma1, nbr0, pmap1,
                                                    pmm, slots, n1);
    k_bn1stats<<<1, 64, 0, stream>>>(slots, gamma1, beta1, stats, 1.0f / (float)n0);
    k_conv2<<<(n1 + 511) / 512, B, 0, stream>>>(pmm, W2, b2, nbr1, stats,
                                                x2, slots, n1);
    k_pool2_fc<<<(n2 + B - 1) / B, B, 0, stream>>>(x2, pmap2, slots, gamma2, beta2,
                                                   Wfc, bfc, (float*)d_out,
                                                   n2, 1.0f / (float)n1);
}

// Round 12
// 75.804 us; speedup vs baseline: 3.3821x; 3.3821x over previous
//
#include <hip/hip_runtime.h>
#include <hip/hip_fp16.h>

#define EPS 1e-5f
#define NSLOT 64   // spread-slot copies of the stats accumulators (64 floats each)

__device__ __forceinline__ float waveReduceSum(float v) {
    #pragma unroll
    for (int off = 32; off > 0; off >>= 1)
        v += __shfl_down(v, off, 64);
    return v;
}

// Butterfly-compaction reduction: NV stats spread across lanes.
template <int NV>
__device__ __forceinline__ float statReduce(float (&v)[NV], int lane) {
    #pragma unroll
    for (int b = 0; (1 << b) < NV; ++b) {
        const int d = 1 << b;
        const bool hi = (lane >> b) & 1;
        #pragma unroll
        for (int i = 0; i < (NV >> (b + 1)); ++i) {
            float kept = hi ? v[2 * i + 1] : v[2 * i];
            float sent = hi ? v[2 * i] : v[2 * i + 1];
            float recv = __shfl_xor(sent, d, 64);
            v[i] = kept + recv;
        }
    }
    float r = v[0];
    #pragma unroll
    for (int d = NV; d < 64; d <<= 1)
        r += __shfl_xor(r, d, 64);
    return r;
}

__device__ __forceinline__ void unpack8(float4 raw, float* g) {
    const __half2* hp = reinterpret_cast<const __half2*>(&raw);
    #pragma unroll
    for (int q = 0; q < 4; ++q) {
        float2 f = __half22float2(hp[q]);
        g[2 * q] = f.x; g[2 * q + 1] = f.y;
    }
}

__device__ __forceinline__ float4 pack8(const float* g) {
    __half2 hp[4];
    #pragma unroll
    for (int q = 0; q < 4; ++q)
        hp[q] = __floats2half2_rn(g[2 * q], g[2 * q + 1]);
    return *reinterpret_cast<float4*>(hp);
}

// ---------------- K0: zero the slot accumulators (16 KB) + p1's zeros-row ----------------
__global__ __launch_bounds__(256) void k_zero(float4* __restrict__ slots,
                                              float4* __restrict__ p1zrow) {
    const float4 z4 = {0.f, 0.f, 0.f, 0.f};
    #pragma unroll
    for (int q = 0; q < 4; ++q)
        slots[q * 256 + threadIdx.x] = z4;
    if (threadIdx.x == 0) p1zrow[0] = z4;   // fp16 zeros == bit-zeros
}

// ---------------- K1: sparse conv1 (1 -> 8), fp16 x1 rows (16 B), BN1-stat partials ----------------
__global__ __launch_bounds__(256, 4) void k_conv1(
        const float* __restrict__ f0, const float* __restrict__ W1,
        const float* __restrict__ b1, const int* __restrict__ nbr0,
        float4* __restrict__ x1h, float* __restrict__ slots, int n0) {
    __shared__ float sred[16];
    int t = threadIdx.x;
    int lane = t & 63;
    if (t < 16) sred[t] = 0.f;
    __syncthreads();

    int n = blockIdx.x * blockDim.x + t;
    bool valid = (n < n0);
    int nn = valid ? n : (n0 - 1);

    int idx[9];
    #pragma unroll
    for (int k = 0; k < 9; ++k) idx[k] = nbr0[(size_t)nn * 9 + k];
    float v[9];
    #pragma unroll
    for (int k = 0; k < 9; ++k) {
        float f = f0[idx[k] >= 0 ? idx[k] : 0];
        v[k] = (idx[k] >= 0) ? f : 0.f;
    }

    float acc[8];
    #pragma unroll
    for (int c = 0; c < 8; ++c) acc[c] = b1[c];
    #pragma unroll
    for (int k = 0; k < 9; ++k)
        #pragma unroll
        for (int c = 0; c < 8; ++c) acc[c] = fmaf(v[k], W1[k * 8 + c], acc[c]);

    if (valid) x1h[n] = pack8(acc);
    else {
        #pragma unroll
        for (int c = 0; c < 8; ++c) acc[c] = 0.f;
    }

    float red[16];
    #pragma unroll
    for (int c = 0; c < 8; ++c) {
        red[c] = acc[c];
        red[8 + c] = acc[c] * acc[c];
    }
    float tot = statReduce<16>(red, lane);
    if (lane < 16) atomicAdd(&sred[lane], tot);
    __syncthreads();
    if (t < 16)
        atomicAdd(&slots[(size_t)(blockIdx.x & (NSLOT - 1)) * 64 + t], sred[t]);
}

// ---------------- K1b: 1-block finalize of BN1 -> folded constants (sc, b0) ----------------
__global__ __launch_bounds__(64) void k_bn1stats(
        const float* __restrict__ slots, const float* __restrict__ gamma1,
        const float* __restrict__ beta1, float* __restrict__ stats, float invn0) {
    __shared__ float st[16];
    int t = threadIdx.x;
    if (t < 16) {
        float s = 0.f;
        #pragma unroll 8
        for (int k = 0; k < NSLOT; ++k) s += slots[(size_t)k * 64 + t];
        st[t] = s;
    }
    __syncthreads();
    if (t < 8) {
        float mu  = st[t] * invn0;
        float var = st[8 + t] * invn0 - mu * mu;
        float sc  = rsqrtf(var + EPS) * gamma1[t];
        stats[t]     = sc;
        stats[8 + t] = beta1[t] - sc * mu;
    }
}

// ---------------- K2: BN1+ReLU (folded consts, uniform loads) fused into 2x2 max pool.
//                      p1 stored fp16 POST-activation (16 B rows). ----------------
__global__ __launch_bounds__(256, 4) void k_pool1(
        const float4* __restrict__ x1h, const int* __restrict__ pmap1,
        const float* __restrict__ stats, float4* __restrict__ p1h, int n1) {
    int i = blockIdx.x * blockDim.x + threadIdx.x;
    if (i >= n1) return;

    int4 pm = ((const int4*)pmap1)[i];
    int idx[4] = {pm.x, pm.y, pm.z, pm.w};
    float best[8];
    #pragma unroll
    for (int c = 0; c < 8; ++c) best[c] = 0.f;  // relu >= 0, >=1 child exists
    #pragma unroll
    for (int k = 0; k < 4; ++k) {
        float4 raw = x1h[idx[k] >= 0 ? idx[k] : 0];
        float v[8];
        unpack8(raw, v);
        #pragma unroll
        for (int c = 0; c < 8; ++c) {
            float z = fmaxf(fmaf(v[c], stats[c], stats[8 + c]), 0.f);
            z = (idx[k] >= 0) ? z : 0.f;
            best[c] = fmaxf(best[c], z);
        }
    }
    p1h[i] = pack8(best);
}

// ---------------- K3: sparse conv2 (8 -> 16). p1 is fp16 pre-activated; missing
//                      taps hit the zeros-row at n1 (unconditional gather). ----------------
__global__ __launch_bounds__(256, 4) void k_conv2(
        const float4* __restrict__ p1h, const float* __restrict__ W2,
        const float* __restrict__ b2, const int* __restrict__ nbr1,
        float* __restrict__ x2, float* __restrict__ slots, int n1) {
    __shared__ float sred[32];
    int t = threadIdx.x;
    int lane = t & 63;
    if (t < 32) sred[t] = 0.f;
    __syncthreads();

    int n = blockIdx.x * blockDim.x + t;
    bool valid = (n < n1);
    int nn = valid ? n : (n1 - 1);

    int idx[9];
    #pragma unroll
    for (int k = 0; k < 9; ++k) {
        int j = nbr1[(size_t)nn * 9 + k];
        idx[k] = (j >= 0) ? j : n1;          // zeros-row
    }

    float acc[16];
    #pragma unroll
    for (int c = 0; c < 16; ++c) acc[c] = b2[c];

    #pragma unroll
    for (int k = 0; k < 9; ++k) {
        float4 raw = p1h[idx[k]];
        float g[8];
        unpack8(raw, g);
        #pragma unroll
        for (int ci = 0; ci < 8; ++ci) {
            #pragma unroll
            for (int c = 0; c < 16; ++c)
                acc[c] = fmaf(g[ci], W2[(k * 8 + ci) * 16 + c], acc[c]);
        }
    }

    if (valid) {
        float4* dst = (float4*)(x2 + (size_t)n * 16);
        #pragma unroll
        for (int q4 = 0; q4 < 4; ++q4)
            dst[q4] = make_float4(acc[q4 * 4], acc[q4 * 4 + 1],
                                  acc[q4 * 4 + 2], acc[q4 * 4 + 3]);
    } else {
        #pragma unroll
        for (int c = 0; c < 16; ++c) acc[c] = 0.f;
    }

    float red[32];
    #pragma unroll
    for (int c = 0; c < 16; ++c) {
        red[c] = acc[c];
        red[16 + c] = acc[c] * acc[c];
    }
    float tot = statReduce<32>(red, lane);
    if (lane < 32) atomicAdd(&sred[lane], tot);
    __syncthreads();
    if (t < 32)
        atomicAdd(&slots[(size_t)(blockIdx.x & (NSLOT - 1)) * 64 + 16 + t], sred[t]);
}

// ---------------- K4: finalize BN2 stats + BN2+ReLU fused into pool + FC(16->2) ----------------
__global__ __launch_bounds__(256) void k_pool2_fc(
        const float* __restrict__ x2, const int* __restrict__ pmap2,
        const float* __restrict__ slots, const float* __restrict__ gamma2,
        const float* __restrict__ beta2, const float* __restrict__ Wfc,
        const float* __restrict__ bfc, float* __restrict__ out,
        int n2, float invn) {
    __shared__ float sstat[32];
    int t = threadIdx.x;
    if (t < 64) {
        const float4* s4 = (const float4*)(slots + (size_t)t * 64 + 16);
        float vals[32];
        #pragma unroll
        for (int q = 0; q < 8; ++q) {
            float4 a = s4[q];
            vals[q * 4 + 0] = a.x; vals[q * 4 + 1] = a.y;
            vals[q * 4 + 2] = a.z; vals[q * 4 + 3] = a.w;
        }
        #pragma unroll
        for (int c = 0; c < 32; ++c) {
            float s = waveReduceSum(vals[c]);
            if (t == 0) sstat[c] = s;
        }
    }
    __syncthreads();

    int i = blockIdx.x * blockDim.x + t;
    if (i >= n2) return;

    float m[16], sc[16], bb[16];
    #pragma unroll
    for (int c = 0; c < 16; ++c) {
        float mu  = sstat[c] * invn;
        float var = sstat[16 + c] * invn - mu * mu;
        m[c]  = mu;
        sc[c] = rsqrtf(var + EPS) * gamma2[c];
        bb[c] = beta2[c];
    }

    int4 pm = ((const int4*)pmap2)[i];
    int idx[4] = {pm.x, pm.y, pm.z, pm.w};
    float best[16];
    #pragma unroll
    for (int c = 0; c < 16; ++c) best[c] = 0.f;
    #pragma unroll
    for (int k = 0; k < 4; ++k) {
        int j = idx[k] >= 0 ? idx[k] : 0;
        const float4* src = (const float4*)(x2 + (size_t)j * 16);
        #pragma unroll
        for (int q4 = 0; q4 < 4; ++q4) {
            float4 v4 = src[q4];
            float v[4] = {v4.x, v4.y, v4.z, v4.w};
            #pragma unroll
            for (int c = 0; c < 4; ++c) {
                int cc = q4 * 4 + c;
                float z = fmaxf(fmaf(v[c] - m[cc], sc[cc], bb[cc]), 0.f);
                z = (idx[k] >= 0) ? z : 0.f;
                best[cc] = fmaxf(best[cc], z);
            }
        }
    }
    float o0 = bfc[0], o1 = bfc[1];
    #pragma unroll
    for (int c = 0; c < 16; ++c) {
        o0 = fmaf(best[c], Wfc[c * 2 + 0], o0);
        o1 = fmaf(best[c], Wfc[c * 2 + 1], o1);
    }
    out[(size_t)i * 2 + 0] = o0;
    out[(size_t)i * 2 + 1] = o1;
}

extern "C" void kernel_launch(void* const* d_in, const int* in_sizes, int n_in,
                              void* d_out, int out_size, void* d_ws, size_t ws_size,
                              hipStream_t stream) {
    const float* f0     = (const float*)d_in[0];
    const float* W1     = (const float*)d_in[1];
    const float* b1     = (const float*)d_in[2];
    const float* gamma1 = (const float*)d_in[3];
    const float* beta1  = (const float*)d_in[4];
    const float* W2     = (const float*)d_in[5];
    const float* b2     = (const float*)d_in[6];
    const float* gamma2 = (const float*)d_in[7];
    const float* beta2  = (const float*)d_in[8];
    const float* Wfc    = (const float*)d_in[9];
    const float* bfc    = (const float*)d_in[10];
    const int*   nbr0   = (const int*)d_in[11];
    const int*   pmap1  = (const int*)d_in[12];
    const int*   nbr1   = (const int*)d_in[13];
    const int*   pmap2  = (const int*)d_in[14];

    const int n0 = in_sizes[0];
    const int n1 = in_sizes[12] / 4;
    const int n2 = in_sizes[14] / 4;

    float*  ws    = (float*)d_ws;
    float*  slots = ws;                                  // NSLOT*64 f32 (16 KB)
    float*  stats = ws + (size_t)NSLOT * 64;             // 16 f32 (sc1, b01)
    float4* x1h   = (float4*)(stats + 16);               // n0 rows   x 16 B (fp16x8)
    float4* p1h   = x1h + n0;                            // n1+1 rows x 16 B (fp16x8, row n1 = zeros)
    float*  x2    = (float*)(p1h + n1 + 1);              // n1*16 f32

    const int B = 256;
    k_zero<<<1, B, 0, stream>>>((float4*)slots, p1h + n1);
    k_conv1<<<(n0 + B - 1) / B, B, 0, stream>>>(f0, W1, b1, nbr0, x1h, slots, n0);
    k_bn1stats<<<1, 64, 0, stream>>>(slots, gamma1, beta1, stats, 1.0f / (float)n0);
    k_pool1<<<(n1 + B - 1) / B, B, 0, stream>>>(x1h, pmap1, stats, p1h, n1);
    k_conv2<<<(n1 + B - 1) / B, B, 0, stream>>>(p1h, W2, b2, nbr1, x2, slots, n1);
    k_pool2_fc<<<(n2 + B - 1) / B, B, 0, stream>>>(x2, pmap2, slots, gamma2, beta2,
                                                   Wfc, bfc, (float*)d_out,
                                                   n2, 1.0f / (float)n1);
}